// Round 5
// baseline (1633.389 us; speedup 1.0000x reference)
//
#include <hip/hip_runtime.h>
#include <hip/hip_bf16.h>

// Elman RNN, round 5.
// Phase 1 (1024 blocks = 128 batch x 8 t-chunks): xin[t][b][h] =
//   bf16( log2e*(x[b,t,:].W_in[h,:] + b_in[h]) ), MFMA with t on the n-axis so
//   x reads stay inside an 8KB window per iteration (was 1MB-strided).
// Phase 2 (8 blocks x 16 batch, 512 thr = 8 waves): scan
//   h' = sigmoid(xin_t + h.W_rec^T)  via  rcp(1 + exp2(-z)), z pre-scaled by log2e.
//   h lives in a 2-buffer XOR-swizzled LDS layout: row = batch (512B), 16B slot s
//   stored at s ^ (n15&7)  -> both the C-layout writes and B-fragment reads are
//   bank-conflict-minimal (rows 8 apart alias 2-way = free). 2-step unrolled loop,
//   distance-2 xin prefetch with scalar-base addressing, precomputed LDS addrs.

#define BATCH 128
#define SEQ   2048
#define NIN   128
#define NH    256
#define NOUT  128

#define BTILE 16
#define NBLK  (BATCH / BTILE)      // 8
#define HROW  256                  // elems per h row (512 B, no pad; XOR swizzle)
#define HBUF  (BTILE * HROW)       // 4096 elems = 8192 B per buffer
#define LOG2E 1.4426950408889634f

// fallback-only (round-4 layout)
#define HPITCH 264
#define XPITCH 136

typedef __attribute__((ext_vector_type(8))) short short8;
typedef __attribute__((ext_vector_type(4))) float f32x4;

__device__ __forceinline__ ushort f2bf(float f) {
    union { float f; uint u; } v; v.f = f;
    uint r = v.u + 0x7fffu + ((v.u >> 16) & 1u);   // RNE
    return (ushort)(r >> 16);
}
__device__ __forceinline__ uint pk_bf16(float a, float b) {
    float2 p; p.x = a; p.y = b;
    __hip_bfloat162 h = __float22bfloat162_rn(p);
    union { __hip_bfloat162 h; uint u; } v; v.h = h; return v.u;
}
__device__ __forceinline__ short8 load_wfrag_s(const float* __restrict__ W, int ld,
                                               int row, int col, float scale) {
    const float4* p = (const float4*)(W + (size_t)row * ld + col);
    float4 a = p[0], b = p[1];
    union { short8 v; uint u[4]; } r;
    r.u[0] = pk_bf16(a.x * scale, a.y * scale);
    r.u[1] = pk_bf16(a.z * scale, a.w * scale);
    r.u[2] = pk_bf16(b.x * scale, b.y * scale);
    r.u[3] = pk_bf16(b.z * scale, b.w * scale);
    return r.v;
}
__device__ __forceinline__ float bfhi2f(uint u) {
    union { uint u; float f; } v; v.u = u & 0xffff0000u; return v.f;
}
__device__ __forceinline__ float bflo2f(uint u) {
    union { uint u; float f; } v; v.u = u << 16; return v.f;
}

// ---------------- Phase 1: xin = log2e*(x.W_in^T + b_in), t on n-axis ----------
__global__ __launch_bounds__(256, 4)
void xin_gemm(const float* __restrict__ x,
              const float* __restrict__ W_in,
              const float* __restrict__ b_in,
              ushort* __restrict__ xin) {
    const int tid  = threadIdx.x;
    const int lane = tid & 63;
    const int wid  = tid >> 6;          // 0..3
    const int n15  = lane & 15;         // t within 16-t tile
    const int q    = lane >> 4;
    const int b    = blockIdx.x;        // batch row
    const int t0   = blockIdx.y * 256;  // t chunk

    // A-fragments of W_in (scaled): wave wid owns hidden m-tiles wid*4..wid*4+3
    short8 win[4][4];
    float  bias[4][4];
    #pragma unroll
    for (int mt = 0; mt < 4; ++mt) {
        const int row = (wid * 4 + mt) * 16 + n15;
        #pragma unroll
        for (int kt = 0; kt < 4; ++kt)
            win[mt][kt] = load_wfrag_s(W_in, NIN, row, kt * 32 + q * 8, LOG2E);
        #pragma unroll
        for (int r = 0; r < 4; ++r)
            bias[mt][r] = LOG2E * b_in[(wid * 4 + mt) * 16 + q * 4 + r];
    }

    const float* xb = x + ((size_t)b * SEQ + t0 + n15) * NIN + q * 8;
    size_t xo = ((size_t)(t0 + n15) * BATCH + b) * NH + q * 4;

    #pragma unroll 1
    for (int it = 0; it < 16; ++it) {
        // B-fragments: n = t (n15), k = input i
        short8 bx[4];
        #pragma unroll
        for (int kt = 0; kt < 4; ++kt) {
            const float4* p = (const float4*)(xb + kt * 32);
            float4 a = p[0], c = p[1];
            union { short8 v; uint u[4]; } r;
            r.u[0] = pk_bf16(a.x, a.y); r.u[1] = pk_bf16(a.z, a.w);
            r.u[2] = pk_bf16(c.x, c.y); r.u[3] = pk_bf16(c.z, c.w);
            bx[kt] = r.v;
        }
        f32x4 acc[4];
        #pragma unroll
        for (int mt = 0; mt < 4; ++mt) {
            acc[mt][0] = bias[mt][0]; acc[mt][1] = bias[mt][1];
            acc[mt][2] = bias[mt][2]; acc[mt][3] = bias[mt][3];
        }
        #pragma unroll
        for (int kt = 0; kt < 4; ++kt)
            #pragma unroll
            for (int mt = 0; mt < 4; ++mt)
                acc[mt] = __builtin_amdgcn_mfma_f32_16x16x32_bf16(
                    win[mt][kt], bx[kt], acc[mt], 0, 0, 0);
        // C: col(lane&15)=t, rows = hidden (q*4+r within mtile*16)
        #pragma unroll
        for (int mt = 0; mt < 4; ++mt) {
            uint2 w;
            w.x = pk_bf16(acc[mt][0], acc[mt][1]);
            w.y = pk_bf16(acc[mt][2], acc[mt][3]);
            *(uint2*)&xin[xo + (wid * 4 + mt) * 16] = w;
        }
        xb += 16 * NIN;
        xo += (size_t)16 * BATCH * NH;
    }
}

// ---------------- Phase 2: scan + output projection ----------------
__global__ __launch_bounds__(512, 2)
void elman_scan(const ushort* __restrict__ xin,
                const float* __restrict__ W_rec,
                const float* __restrict__ W_out,
                const float* __restrict__ b_out,
                float* __restrict__ out) {
    const int tid  = threadIdx.x;
    const int lane = tid & 63;
    const int wid  = tid >> 6;          // 0..7
    const int n15  = lane & 15;         // batch within tile
    const int q    = lane >> 4;
    const int key  = n15 & 7;           // per-row XOR swizzle key
    const int bblk = blockIdx.x * BTILE;

    __shared__ __align__(16) ushort hl[2 * HBUF];  // 16 KB, buffers 8192 B apart

    // W_rec A-fragments (scaled by log2e): wave owns m-tiles wid*2, wid*2+1
    short8 wrec[2][8];
    #pragma unroll
    for (int mt = 0; mt < 2; ++mt) {
        const int row = (wid * 2 + mt) * 16 + n15;
        #pragma unroll
        for (int kt = 0; kt < 8; ++kt)
            wrec[mt][kt] = load_wfrag_s(W_rec, NH, row, kt * 32 + q * 8, LOG2E);
    }

    // Precomputed swizzled LDS addresses (element indices into hl, buffer 0).
    // Read: slot s = 4*kt+q stored at s^key.  Write (mtile,q): slot 2*mtile+(q>>1),
    // half (q&1).
    int raddr[8];
    #pragma unroll
    for (int kt = 0; kt < 8; ++kt)
        raddr[kt] = n15 * HROW + (((kt * 4 + q) ^ key) * 8);
    int waddr[2];
    #pragma unroll
    for (int mt = 0; mt < 2; ++mt) {
        const int mtile = wid * 2 + mt;
        waddr[mt] = n15 * HROW + (((2 * mtile + (q >> 1)) ^ key) * 8) + (q & 1) * 4;
    }

    // h0 = 0 (buffer 0)
    #pragma unroll
    for (int i = tid; i < HBUF / 2; i += 512)
        ((uint*)hl)[i] = 0u;

    // xin element consumed by this lane at step t:
    // [t][bblk+n15][(wid*2+mt)*16 + q*4 .. +3]
    const int xoff = (bblk + n15) * NH + q * 4 + (wid * 2) * 16;  // + mt*16
    const size_t tstride = (size_t)BATCH * NH;                    // 32768 elems

    uint2 xc0[2], xc1[2];   // xin for t, t+1
    #pragma unroll
    for (int mt = 0; mt < 2; ++mt) {
        xc0[mt] = *(const uint2*)(xin + xoff + mt * 16);
        xc1[mt] = *(const uint2*)(xin + tstride + xoff + mt * 16);
    }
    __syncthreads();

    #pragma unroll 1
    for (int t = 0; t < SEQ; t += 2) {
        // distance-2 prefetch (uniform scalar base + fixed lane offset)
        const int tp2 = (t + 2 < SEQ) ? (t + 2) : (SEQ - 1);
        const int tp3 = (t + 3 < SEQ) ? (t + 3) : (SEQ - 1);
        const ushort* b2 = xin + (size_t)tp2 * tstride;
        const ushort* b3 = xin + (size_t)tp3 * tstride;
        uint2 xn0[2], xn1[2];
        #pragma unroll
        for (int mt = 0; mt < 2; ++mt) {
            xn0[mt] = *(const uint2*)(b2 + xoff + mt * 16);
            xn1[mt] = *(const uint2*)(b3 + xoff + mt * 16);
        }

        // ---- step t: buf0 -> buf1 ----
        {
            short8 bh[8];
            #pragma unroll
            for (int kt = 0; kt < 8; ++kt)
                bh[kt] = *(const short8*)&hl[raddr[kt]];
            f32x4 acc[2];
            #pragma unroll
            for (int mt = 0; mt < 2; ++mt) {
                acc[mt][0] = bflo2f(xc0[mt].x);
                acc[mt][1] = bfhi2f(xc0[mt].x);
                acc[mt][2] = bflo2f(xc0[mt].y);
                acc[mt][3] = bfhi2f(xc0[mt].y);
            }
            #pragma unroll
            for (int kt = 0; kt < 8; ++kt)
                #pragma unroll
                for (int mt = 0; mt < 2; ++mt)
                    acc[mt] = __builtin_amdgcn_mfma_f32_16x16x32_bf16(
                        wrec[mt][kt], bh[kt], acc[mt], 0, 0, 0);
            #pragma unroll
            for (int mt = 0; mt < 2; ++mt) {
                float h0 = __builtin_amdgcn_rcpf(1.0f + __builtin_amdgcn_exp2f(-acc[mt][0]));
                float h1 = __builtin_amdgcn_rcpf(1.0f + __builtin_amdgcn_exp2f(-acc[mt][1]));
                float h2 = __builtin_amdgcn_rcpf(1.0f + __builtin_amdgcn_exp2f(-acc[mt][2]));
                float h3 = __builtin_amdgcn_rcpf(1.0f + __builtin_amdgcn_exp2f(-acc[mt][3]));
                uint2 w;
                w.x = pk_bf16(h0, h1);
                w.y = pk_bf16(h2, h3);
                *(uint2*)&hl[HBUF + waddr[mt]] = w;
            }
            __syncthreads();
        }
        // ---- step t+1: buf1 -> buf0 ----
        {
            short8 bh[8];
            #pragma unroll
            for (int kt = 0; kt < 8; ++kt)
                bh[kt] = *(const short8*)&hl[HBUF + raddr[kt]];
            f32x4 acc[2];
            #pragma unroll
            for (int mt = 0; mt < 2; ++mt) {
                acc[mt][0] = bflo2f(xc1[mt].x);
                acc[mt][1] = bfhi2f(xc1[mt].x);
                acc[mt][2] = bflo2f(xc1[mt].y);
                acc[mt][3] = bfhi2f(xc1[mt].y);
            }
            #pragma unroll
            for (int kt = 0; kt < 8; ++kt)
                #pragma unroll
                for (int mt = 0; mt < 2; ++mt)
                    acc[mt] = __builtin_amdgcn_mfma_f32_16x16x32_bf16(
                        wrec[mt][kt], bh[kt], acc[mt], 0, 0, 0);
            #pragma unroll
            for (int mt = 0; mt < 2; ++mt) {
                float h0 = __builtin_amdgcn_rcpf(1.0f + __builtin_amdgcn_exp2f(-acc[mt][0]));
                float h1 = __builtin_amdgcn_rcpf(1.0f + __builtin_amdgcn_exp2f(-acc[mt][1]));
                float h2 = __builtin_amdgcn_rcpf(1.0f + __builtin_amdgcn_exp2f(-acc[mt][2]));
                float h3 = __builtin_amdgcn_rcpf(1.0f + __builtin_amdgcn_exp2f(-acc[mt][3]));
                uint2 w;
                w.x = pk_bf16(h0, h1);
                w.y = pk_bf16(h2, h3);
                *(uint2*)&hl[waddr[mt]] = w;
            }
            __syncthreads();
        }

        #pragma unroll
        for (int mt = 0; mt < 2; ++mt) { xc0[mt] = xn0[mt]; xc1[mt] = xn1[mt]; }
    }

    // ---- output projection from buffer 0 (SEQ even): wave wid owns m-tile wid ----
    short8 wout[8];
    float  bo[4];
    {
        const int row = wid * 16 + n15;
        #pragma unroll
        for (int kt = 0; kt < 8; ++kt)
            wout[kt] = load_wfrag_s(W_out, NH, row, kt * 32 + q * 8, 1.0f);
        #pragma unroll
        for (int r = 0; r < 4; ++r)
            bo[r] = b_out[wid * 16 + q * 4 + r];
    }
    f32x4 oacc;
    oacc[0] = bo[0]; oacc[1] = bo[1]; oacc[2] = bo[2]; oacc[3] = bo[3];
    #pragma unroll
    for (int kt = 0; kt < 8; ++kt) {
        short8 bh = *(const short8*)&hl[raddr[kt]];
        oacc = __builtin_amdgcn_mfma_f32_16x16x32_bf16(wout[kt], bh, oacc, 0, 0, 0);
    }
    #pragma unroll
    for (int r = 0; r < 4; ++r) {
        const int o = wid * 16 + q * 4 + r;
        out[(size_t)(bblk + n15) * NOUT + o] = oacc[r];
    }
}

// ---------------- Fallback (fully fused) if ws too small ----------------
__global__ __launch_bounds__(256, 1)
void elman_mfma(const float* __restrict__ x,
                const float* __restrict__ W_in,
                const float* __restrict__ b_in,
                const float* __restrict__ W_rec,
                const float* __restrict__ W_out,
                const float* __restrict__ b_out,
                float* __restrict__ out) {
    const int tid  = threadIdx.x;
    const int lane = tid & 63;
    const int wid  = tid >> 6;
    const int n15  = lane & 15;
    const int q    = lane >> 4;
    const int bblk = blockIdx.x * BTILE;

    __shared__ __align__(16) ushort hlds[2][BTILE * HPITCH];
    __shared__ __align__(16) ushort xlds[2][BTILE * XPITCH];

    short8 wrec[4][8];
    short8 win[4][4];
    float  bias[4][4];
    #pragma unroll
    for (int mt = 0; mt < 4; ++mt) {
        const int row = (wid * 4 + mt) * 16 + n15;
        #pragma unroll
        for (int kt = 0; kt < 8; ++kt)
            wrec[mt][kt] = load_wfrag_s(W_rec, NH, row, kt * 32 + q * 8, 1.0f);
        #pragma unroll
        for (int kt = 0; kt < 4; ++kt)
            win[mt][kt] = load_wfrag_s(W_in, NIN, row, kt * 32 + q * 8, 1.0f);
        #pragma unroll
        for (int r = 0; r < 4; ++r)
            bias[mt][r] = b_in[(wid * 4 + mt) * 16 + q * 4 + r];
    }
    for (int i = tid; i < BTILE * HPITCH / 2; i += 256)
        ((uint*)hlds[0])[i] = 0u;

    const int xr = tid >> 4;
    const int xc = (tid & 15) * 8;
    const size_t xbase = ((size_t)(bblk + xr)) * SEQ * NIN + xc;
    {
        const float4* p = (const float4*)(x + xbase);
        float4 a = p[0], b = p[1];
        union { uint4 u4; uint s[4]; } px;
        px.s[0] = pk_bf16(a.x, a.y); px.s[1] = pk_bf16(a.z, a.w);
        px.s[2] = pk_bf16(b.x, b.y); px.s[3] = pk_bf16(b.z, b.w);
        *(uint4*)&xlds[0][xr * XPITCH + xc] = px.u4;
    }
    __syncthreads();

    #pragma unroll 1
    for (int t = 0; t < SEQ; ++t) {
        const int cur = t & 1, nxt = cur ^ 1;
        float4 xp0{}, xp1{};
        if (t + 1 < SEQ) {
            const float4* p = (const float4*)(x + xbase + (size_t)(t + 1) * NIN);
            xp0 = p[0]; xp1 = p[1];
        }
        short8 bx[4], bh[8];
        #pragma unroll
        for (int kt = 0; kt < 4; ++kt)
            bx[kt] = *(const short8*)&xlds[cur][n15 * XPITCH + kt * 32 + q * 8];
        #pragma unroll
        for (int kt = 0; kt < 8; ++kt)
            bh[kt] = *(const short8*)&hlds[cur][n15 * HPITCH + kt * 32 + q * 8];
        f32x4 acc[4];
        #pragma unroll
        for (int mt = 0; mt < 4; ++mt) {
            acc[mt][0] = bias[mt][0]; acc[mt][1] = bias[mt][1];
            acc[mt][2] = bias[mt][2]; acc[mt][3] = bias[mt][3];
        }
        #pragma unroll
        for (int kt = 0; kt < 4; ++kt)
            #pragma unroll
            for (int mt = 0; mt < 4; ++mt)
                acc[mt] = __builtin_amdgcn_mfma_f32_16x16x32_bf16(
                    win[mt][kt], bx[kt], acc[mt], 0, 0, 0);
        #pragma unroll
        for (int kt = 0; kt < 8; ++kt)
            #pragma unroll
            for (int mt = 0; mt < 4; ++mt)
                acc[mt] = __builtin_amdgcn_mfma_f32_16x16x32_bf16(
                    wrec[mt][kt], bh[kt], acc[mt], 0, 0, 0);
        #pragma unroll
        for (int mt = 0; mt < 4; ++mt) {
            float h0 = 1.0f / (1.0f + __expf(-acc[mt][0]));
            float h1 = 1.0f / (1.0f + __expf(-acc[mt][1]));
            float h2 = 1.0f / (1.0f + __expf(-acc[mt][2]));
            float h3 = 1.0f / (1.0f + __expf(-acc[mt][3]));
            uint2 w;
            w.x = pk_bf16(h0, h1);
            w.y = pk_bf16(h2, h3);
            *(uint2*)&hlds[nxt][n15 * HPITCH + (wid * 4 + mt) * 16 + q * 4] = w;
        }
        if (t + 1 < SEQ) {
            union { uint4 u4; uint s[4]; } px;
            px.s[0] = pk_bf16(xp0.x, xp0.y); px.s[1] = pk_bf16(xp0.z, xp0.w);
            px.s[2] = pk_bf16(xp1.x, xp1.y); px.s[3] = pk_bf16(xp1.z, xp1.w);
            *(uint4*)&xlds[nxt][xr * XPITCH + xc] = px.u4;
        }
        __syncthreads();
    }

    short8 wout[2][8];
    float  bo[2][4];
    #pragma unroll
    for (int mo = 0; mo < 2; ++mo) {
        const int row = (wid * 2 + mo) * 16 + n15;
        #pragma unroll
        for (int kt = 0; kt < 8; ++kt)
            wout[mo][kt] = load_wfrag_s(W_out, NH, row, kt * 32 + q * 8, 1.0f);
        #pragma unroll
        for (int r = 0; r < 4; ++r)
            bo[mo][r] = b_out[(wid * 2 + mo) * 16 + q * 4 + r];
    }
    f32x4 oacc[2];
    #pragma unroll
    for (int mo = 0; mo < 2; ++mo) {
        oacc[mo][0] = bo[mo][0]; oacc[mo][1] = bo[mo][1];
        oacc[mo][2] = bo[mo][2]; oacc[mo][3] = bo[mo][3];
    }
    #pragma unroll
    for (int kt = 0; kt < 8; ++kt) {
        short8 bh = *(const short8*)&hlds[0][n15 * HPITCH + kt * 32 + q * 8];
        #pragma unroll
        for (int mo = 0; mo < 2; ++mo)
            oacc[mo] = __builtin_amdgcn_mfma_f32_16x16x32_bf16(
                wout[mo][kt], bh, oacc[mo], 0, 0, 0);
    }
    #pragma unroll
    for (int mo = 0; mo < 2; ++mo)
        #pragma unroll
        for (int r = 0; r < 4; ++r) {
            const int o = (wid * 2 + mo) * 16 + q * 4 + r;
            out[(size_t)(bblk + n15) * NOUT + o] = oacc[mo][r];
        }
}

extern "C" void kernel_launch(void* const* d_in, const int* in_sizes, int n_in,
                              void* d_out, int out_size, void* d_ws, size_t ws_size,
                              hipStream_t stream) {
    const float* x     = (const float*)d_in[0];
    const float* W_in  = (const float*)d_in[1];
    const float* b_in  = (const float*)d_in[2];
    const float* W_rec = (const float*)d_in[3];
    const float* W_out = (const float*)d_in[4];
    const float* b_out = (const float*)d_in[5];
    float* out = (float*)d_out;

    const size_t need = (size_t)SEQ * BATCH * NH * sizeof(ushort);  // 134 MB
    if (ws_size >= need) {
        ushort* xin = (ushort*)d_ws;
        dim3 g1(BATCH, SEQ / 256);     // 128 x 8 = 1024 blocks
        xin_gemm<<<g1, 256, 0, stream>>>(x, W_in, b_in, xin);
        elman_scan<<<NBLK, 512, 0, stream>>>(xin, W_rec, W_out, b_out, out);
    } else {
        elman_mfma<<<NBLK, 256, 0, stream>>>(x, W_in, b_in, W_rec, W_out, b_out, out);
    }
}